// Round 3
// baseline (51.378 us; speedup 1.0000x reference)
//
#include <hip/hip_runtime.h>

#define BN 64
#define HH 384
#define WW 384
#define NP 96
#define NS 96
#define NPIX (HH * WW)
#define PXT 16                // pixels per thread (row-aligned: 16 | 384)
#define TPB 256
#define PXB (PXT * TPB)       // 4096 px per block
#define NBX (NPIX / PXB)      // 36

// d_ws layout:
//   [0,1024):    int startP[64], cntP[64], startS[64], cntS[64]
//   [1024,4096): float PP[96][8]  (x0,y0,q2,cos | sin,e,b,-)
//   [4096,5632): float SP[96][4]  (x0,y0,-0.5/sig^2,amp)

__device__ __forceinline__ float fast_atan(float t) {
    float a = __builtin_fabsf(t);
    float r = __builtin_amdgcn_rcpf(a);
    bool big = a > 1.0f;
    float u = big ? r : a;
    float u2 = u * u;
    float p = -0.0117212f;
    p = fmaf(p, u2, 0.05265332f);
    p = fmaf(p, u2, -0.11643287f);
    p = fmaf(p, u2, 0.19354346f);
    p = fmaf(p, u2, -0.33262347f);
    p = fmaf(p, u2, 0.99997726f);
    p = p * u;
    p = big ? (1.57079632679f - p) : p;
    return copysignf(p, t);
}

__global__ void lens_setup(
    const float* __restrict__ pemd_params,    // [NP,6]
    const float* __restrict__ precomp_params, // [NP,4]
    const float* __restrict__ source_params,  // [NS,4]
    const int*   __restrict__ batch_idx,      // [BN]
    const int*   __restrict__ pemd_sys_idx,   // [NP]
    const int*   __restrict__ precomp_map,    // [4]
    const int*   __restrict__ source_sys_idx, // [NS]
    int* __restrict__ ws_i, float* __restrict__ wsP, float* __restrict__ wsS)
{
    __shared__ int sBI[BN];
    __shared__ int nbP[NP], nbS[NS];
    __shared__ int cP[BN], cS[BN], stP[BN], stS[BN];
    const int t = threadIdx.x;  // 128 threads

    if (t < BN) sBI[t] = batch_idx[t];
    __syncthreads();

    if (t < NP) {
        int sys = pemd_sys_idx[t];
        int nb = -1;
        for (int k = 0; k < BN; ++k) if (sBI[k] == sys) { nb = k; break; }
        nbP[t] = nb;
        int sys2 = source_sys_idx[t];
        int nb2 = -1;
        for (int k = 0; k < BN; ++k) if (sBI[k] == sys2) { nb2 = k; break; }
        nbS[t] = nb2;
    }
    __syncthreads();

    if (t < BN) {
        int c = 0, c2 = 0;
        for (int m = 0; m < NP; ++m) { c += (nbP[m] == t); c2 += (nbS[m] == t); }
        cP[t] = c; cS[t] = c2;
    }
    __syncthreads();

    if (t < BN) {
        int s = 0, s2 = 0;
        for (int b = 0; b < t; ++b) { s += cP[b]; s2 += cS[b]; }
        stP[t] = s; stS[t] = s2;
        ws_i[t] = s; ws_i[64 + t] = cP[t];
        ws_i[128 + t] = s2; ws_i[192 + t] = cS[t];
    }
    __syncthreads();

    if (t < NP) {
        int nb = nbP[t];
        if (nb >= 0) {
            int pos = 0;
            for (int m = 0; m < t; ++m) pos += (nbP[m] == nb);
            const float* p = pemd_params + t * 6;
            float x0 = p[0], y0 = p[1], q = p[2], phi = p[3], thE = p[4];
            float sn, cs;
            __sincosf(phi, &sn, &cs);
            float q2 = q * q;
            float e = sqrtf(fmaxf(1.0f - q2, 1e-8f));
            float scale = precomp_params[t * 4 + precomp_map[0]];
            float bco = thE * scale * q / e;
            int gp = stP[nb] + pos;
            float4* w = (float4*)wsP;
            w[gp * 2]     = make_float4(x0, y0, q2, cs);
            w[gp * 2 + 1] = make_float4(sn, e, bco, 0.0f);
        }
        int nb2 = nbS[t];
        if (nb2 >= 0) {
            int pos = 0;
            for (int m = 0; m < t; ++m) pos += (nbS[m] == nb2);
            const float* p = source_params + t * 4;
            float sg = p[2];
            ((float4*)wsS)[stS[nb2] + pos] =
                make_float4(p[0], p[1], -0.5f / (sg * sg), p[3]);
        }
    }
}

__global__ __launch_bounds__(TPB, 4) void lens_main(
    const float* __restrict__ grid,   // [H*W*2] interleaved
    const int*   __restrict__ ws_i,
    const float* __restrict__ wsP,
    const float* __restrict__ wsS,
    float*       __restrict__ out)    // [B,H,W]
{
    const int b = blockIdx.y;
    const int startP = ws_i[b],       nP = ws_i[64 + b];
    const int startS = ws_i[128 + b], nS = ws_i[192 + b];

    // 16 row-aligned pixels per thread: po % 384 in {0,16,...,368} -> one row, one gy
    const int po = blockIdx.x * PXB + threadIdx.x * PXT;
    const float4* g4 = (const float4*)(grid + (size_t)po * 2);
    float gx[PXT];
    float4 v0 = g4[0];
    const float gy = v0.y;
    gx[0] = v0.x; gx[1] = v0.z;
    #pragma unroll
    for (int u = 1; u < PXT / 2; ++u) {
        float4 v = g4[u];
        gx[2 * u] = v.x; gx[2 * u + 1] = v.z;
    }

    float dx[PXT], dy[PXT];
    #pragma unroll
    for (int u = 0; u < PXT; ++u) { dx[u] = 0.f; dy[u] = 0.f; }

    const float4* P4 = (const float4*)wsP;
    float4 c0 = make_float4(0, 0, 0, 0), c1 = c0, f0 = c0, f1 = c0;
    if (nP > 0) { c0 = P4[2 * startP]; c1 = P4[2 * startP + 1]; }
    for (int n = 0; n < nP; ++n) {
        if (n + 1 < nP) { f0 = P4[2 * (startP + n + 1)]; f1 = P4[2 * (startP + n + 1) + 1]; }
        float x0 = c0.x, y0 = c0.y, q2 = c0.z, cs = c0.w;
        float sn = c1.x, e = c1.y, bco = c1.z;
        float A1 = fmaf(sn, gy, -fmaf(sn, y0, cs * x0));   // xr = cs*gx + A1
        float A2 = fmaf(cs, gy - y0, sn * x0);             // yr = -sn*gx + A2
        #pragma unroll
        for (int u = 0; u < PXT; ++u) {
            float xr = fmaf(cs, gx[u], A1);
            float yr = fmaf(-sn, gx[u], A2);
            float h  = fmaf(q2 * xr, xr, yr * yr);
            float rp = __builtin_amdgcn_rsqf(h + 1e-24f);
            float tx = (e * xr) * rp;
            float ty = (e * yr) * rp;
            float ax = bco * fast_atan(tx);
            // atanh(ty) = ty * P(ty^2), |ty| <= e <= 0.866 -> u2 <= 0.75
            float u2 = ty * ty;
            float pp = 0.04761905f;            // 1/21
            pp = fmaf(pp, u2, 0.05263158f);    // 1/19
            pp = fmaf(pp, u2, 0.05882353f);    // 1/17
            pp = fmaf(pp, u2, 0.06666667f);    // 1/15
            pp = fmaf(pp, u2, 0.07692308f);    // 1/13
            pp = fmaf(pp, u2, 0.09090909f);    // 1/11
            pp = fmaf(pp, u2, 0.11111111f);    // 1/9
            pp = fmaf(pp, u2, 0.14285715f);    // 1/7
            pp = fmaf(pp, u2, 0.2f);           // 1/5
            pp = fmaf(pp, u2, 0.33333334f);    // 1/3
            pp = fmaf(pp, u2, 1.0f);
            float ay = bco * (ty * pp);
            dx[u] = fmaf(cs, ax, dx[u]);
            dx[u] = fmaf(-sn, ay, dx[u]);
            dy[u] = fmaf(sn, ax, dy[u]);
            dy[u] = fmaf(cs, ay, dy[u]);
        }
        c0 = f0; c1 = f1;
    }

    float br[PXT];
    #pragma unroll
    for (int u = 0; u < PXT; ++u) br[u] = 0.f;

    const float4* S4 = (const float4*)wsS;
    float4 s0 = make_float4(0, 0, 0, 0), sN = s0;
    if (nS > 0) s0 = S4[startS];
    for (int n = 0; n < nS; ++n) {
        if (n + 1 < nS) sN = S4[startS + n + 1];
        float x0 = s0.x, k2 = s0.z, amp = s0.w;
        float syc = gy - s0.y;
        #pragma unroll
        for (int u = 0; u < PXT; ++u) {
            float sx = (gx[u] - x0) - dx[u];
            float sy = syc - dy[u];
            float r2 = fmaf(sx, sx, sy * sy);
            br[u] = fmaf(amp, __expf(k2 * r2), br[u]);
        }
        s0 = sN;
    }

    float4* op = (float4*)(out + (size_t)b * NPIX + po);
    #pragma unroll
    for (int u = 0; u < PXT / 4; ++u)
        op[u] = make_float4(br[4 * u], br[4 * u + 1], br[4 * u + 2], br[4 * u + 3]);
}

extern "C" void kernel_launch(void* const* d_in, const int* in_sizes, int n_in,
                              void* d_out, int out_size, void* d_ws, size_t ws_size,
                              hipStream_t stream) {
    const float* lens_grid      = (const float*)d_in[0];
    const float* pemd_params    = (const float*)d_in[1];
    const float* precomp_params = (const float*)d_in[2];
    const float* source_params  = (const float*)d_in[3];
    const int*   batch_idx      = (const int*)d_in[4];
    const int*   pemd_sys_idx   = (const int*)d_in[5];
    // d_in[6] = precomp_sys_idx (unused by the reference computation)
    const int*   precomp_map    = (const int*)d_in[7];
    const int*   source_sys_idx = (const int*)d_in[8];
    float* out = (float*)d_out;

    int*   ws_i = (int*)d_ws;
    float* wsP  = (float*)((char*)d_ws + 1024);
    float* wsS  = (float*)((char*)d_ws + 4096);

    lens_setup<<<1, 128, 0, stream>>>(pemd_params, precomp_params, source_params,
                                      batch_idx, pemd_sys_idx, precomp_map,
                                      source_sys_idx, ws_i, wsP, wsS);

    dim3 grid(NBX, BN, 1);
    lens_main<<<grid, TPB, 0, stream>>>(lens_grid, ws_i, wsP, wsS, out);
}

// Round 4
// 45.402 us; speedup vs baseline: 1.1316x; 1.1316x over previous
//
#include <hip/hip_runtime.h>

#define BN 64
#define HH 384
#define WW 384
#define NP 96
#define NS 96
#define NPIX (HH * WW)
#define PXT 16                // pixels per thread (row-aligned: 16 | 384)
#define TPB 256
#define PXB (PXT * TPB)       // 4096 px per block
#define NBX (NPIX / PXB)      // 36

__device__ __forceinline__ float fast_atan(float t) {
    float a = __builtin_fabsf(t);
    float r = __builtin_amdgcn_rcpf(a);
    bool big = a > 1.0f;
    float u = big ? r : a;
    float u2 = u * u;
    float p = -0.0117212f;
    p = fmaf(p, u2, 0.05265332f);
    p = fmaf(p, u2, -0.11643287f);
    p = fmaf(p, u2, 0.19354346f);
    p = fmaf(p, u2, -0.33262347f);
    p = fmaf(p, u2, 0.99997726f);
    p = p * u;
    p = big ? (1.57079632679f - p) : p;
    return copysignf(p, t);
}

__global__ __launch_bounds__(TPB, 4) void lens_fused(
    const float* __restrict__ grid,           // [H*W*2] interleaved x,y
    const float* __restrict__ pemd_params,    // [NP,6]
    const float* __restrict__ precomp_params, // [NP,4]
    const float* __restrict__ source_params,  // [NS,4]
    const int*   __restrict__ batch_idx,      // [BN]
    const int*   __restrict__ pemd_sys_idx,   // [NP]
    const int*   __restrict__ precomp_map,    // [4]
    const int*   __restrict__ source_sys_idx, // [NS]
    float*       __restrict__ out)            // [B,H,W]
{
    __shared__ float4 sPa[NP];   // x0,y0,q2,cos
    __shared__ float4 sPb[NP];   // sin,e,b,b/2
    __shared__ float4 sS4[NS];   // x0,y0,-0.5/sig^2,amp
    __shared__ int sCnt[4];      // cntP_w0, nP, cntS_w0, nS

    const int tid  = threadIdx.x;
    const int b    = blockIdx.y;
    const int lane = tid & 63;
    const int wv   = tid >> 6;          // 0..3
    const int myB  = batch_idx[b];

    // ---- prologue: parallel membership + ballot compaction ----
    // wave0: PEMD items 0-63   wave1: PEMD items 64-95 (lanes 0-31)
    // wave2: SRC  items 0-63   wave3: SRC  items 64-95 (lanes 0-31)
    const bool isP = (wv < 2);
    const int  item = ((wv & 1) << 6) + lane;
    const bool valid = item < (isP ? NP : NS);

    int sys = -2147483647;
    if (valid) sys = isP ? pemd_sys_idx[item] : source_sys_idx[item];
    bool member = valid && (sys == myB);
    if (member) {  // argmax-first-slot semantics: only the first matching batch slot owns it
        for (int k = 0; k < b; ++k)
            if (batch_idx[k] == sys) { member = false; break; }
    }
    unsigned long long bal = __ballot(member);
    int pos = __popcll(bal & ((1ull << lane) - 1ull));
    int cnt = __popcll(bal);

    if ((wv == 0 || wv == 2) && lane == 0) sCnt[wv] = cnt;

    // wave0/2 member threads can write their entries immediately
    if (member && !(wv & 1)) {
        if (isP) {
            const float* p = pemd_params + item * 6;
            float x0 = p[0], y0 = p[1], q = p[2], phi = p[3], thE = p[4];
            float sn, cs; __sincosf(phi, &sn, &cs);
            float q2 = q * q;
            float e = sqrtf(fmaxf(1.0f - q2, 1e-8f));
            float scale = precomp_params[item * 4 + precomp_map[0]];
            float bco = thE * scale * q / e;
            sPa[pos] = make_float4(x0, y0, q2, cs);
            sPb[pos] = make_float4(sn, e, bco, 0.5f * bco);
        } else {
            const float* p = source_params + item * 4;
            float sg = p[2];
            sS4[pos] = make_float4(p[0], p[1], -0.5f / (sg * sg), p[3]);
        }
    }
    __syncthreads();

    if (wv & 1) {
        int base = sCnt[wv - 1];
        if (lane == 0) sCnt[wv] = base + cnt;   // total count
        if (member) {
            int gp = base + pos;
            if (isP) {
                const float* p = pemd_params + item * 6;
                float x0 = p[0], y0 = p[1], q = p[2], phi = p[3], thE = p[4];
                float sn, cs; __sincosf(phi, &sn, &cs);
                float q2 = q * q;
                float e = sqrtf(fmaxf(1.0f - q2, 1e-8f));
                float scale = precomp_params[item * 4 + precomp_map[0]];
                float bco = thE * scale * q / e;
                sPa[gp] = make_float4(x0, y0, q2, cs);
                sPb[gp] = make_float4(sn, e, bco, 0.5f * bco);
            } else {
                const float* p = source_params + item * 4;
                float sg = p[2];
                sS4[gp] = make_float4(p[0], p[1], -0.5f / (sg * sg), p[3]);
            }
        }
    }
    __syncthreads();

    const int nP = sCnt[1];
    const int nS = sCnt[3];

    // ---- main: 16 row-aligned pixels per thread (one gy per thread) ----
    const int po = blockIdx.x * PXB + tid * PXT;
    const float4* g4 = (const float4*)(grid + (size_t)po * 2);
    float gx[PXT];
    float4 v0 = g4[0];
    const float gy = v0.y;
    gx[0] = v0.x; gx[1] = v0.z;
    #pragma unroll
    for (int u = 1; u < PXT / 2; ++u) {
        float4 v = g4[u];
        gx[2 * u] = v.x; gx[2 * u + 1] = v.z;
    }

    float dx[PXT], dy[PXT];
    #pragma unroll
    for (int u = 0; u < PXT; ++u) { dx[u] = 0.f; dy[u] = 0.f; }

    for (int n = 0; n < nP; ++n) {
        float4 c0 = sPa[n];
        float4 c1 = sPb[n];
        float x0 = c0.x, y0 = c0.y, q2 = c0.z, cs = c0.w;
        float sn = c1.x, e = c1.y, bco = c1.z, hb = c1.w;
        float A1 = fmaf(sn, gy, -fmaf(sn, y0, cs * x0));   // xr =  cs*gx + A1
        float A2 = fmaf(cs, gy - y0, sn * x0);             // yr = -sn*gx + A2
        #pragma unroll
        for (int u = 0; u < PXT; ++u) {
            float xr = fmaf(cs, gx[u], A1);
            float yr = fmaf(-sn, gx[u], A2);
            float h  = fmaf(q2 * xr, xr, yr * yr);
            float rp = __builtin_amdgcn_rsqf(h + 1e-24f);
            float tx = (e * xr) * rp;
            float ty = (e * yr) * rp;
            float ax = bco * fast_atan(tx);
            float tc = fminf(fmaxf(ty, -0.999999f), 0.999999f);
            float L  = __logf((1.0f + tc) * __builtin_amdgcn_rcpf(1.0f - tc));
            float ay = hb * L;
            dx[u] = fmaf(cs, ax, dx[u]);
            dx[u] = fmaf(-sn, ay, dx[u]);
            dy[u] = fmaf(sn, ax, dy[u]);
            dy[u] = fmaf(cs, ay, dy[u]);
        }
    }

    float br[PXT];
    #pragma unroll
    for (int u = 0; u < PXT; ++u) br[u] = 0.f;

    for (int n = 0; n < nS; ++n) {
        float4 sp = sS4[n];
        float x0 = sp.x, k2 = sp.z, amp = sp.w;
        float syc = gy - sp.y;
        #pragma unroll
        for (int u = 0; u < PXT; ++u) {
            float sx = (gx[u] - x0) - dx[u];
            float sy = syc - dy[u];
            float r2 = fmaf(sx, sx, sy * sy);
            br[u] = fmaf(amp, __expf(k2 * r2), br[u]);
        }
    }

    float4* op = (float4*)(out + (size_t)b * NPIX + po);
    #pragma unroll
    for (int u = 0; u < PXT / 4; ++u)
        op[u] = make_float4(br[4 * u], br[4 * u + 1], br[4 * u + 2], br[4 * u + 3]);
}

extern "C" void kernel_launch(void* const* d_in, const int* in_sizes, int n_in,
                              void* d_out, int out_size, void* d_ws, size_t ws_size,
                              hipStream_t stream) {
    const float* lens_grid      = (const float*)d_in[0];
    const float* pemd_params    = (const float*)d_in[1];
    const float* precomp_params = (const float*)d_in[2];
    const float* source_params  = (const float*)d_in[3];
    const int*   batch_idx      = (const int*)d_in[4];
    const int*   pemd_sys_idx   = (const int*)d_in[5];
    // d_in[6] = precomp_sys_idx (unused by the reference computation)
    const int*   precomp_map    = (const int*)d_in[7];
    const int*   source_sys_idx = (const int*)d_in[8];
    float* out = (float*)d_out;

    dim3 grid(NBX, BN, 1);
    lens_fused<<<grid, TPB, 0, stream>>>(lens_grid, pemd_params, precomp_params,
                                         source_params, batch_idx, pemd_sys_idx,
                                         precomp_map, source_sys_idx, out);
}

// Round 6
// 43.087 us; speedup vs baseline: 1.1924x; 1.0537x over previous
//
#include <hip/hip_runtime.h>

#define BN 64
#define HH 384
#define WW 384
#define NP 96
#define NS 96
#define NPIX (HH * WW)
#define TPB 256

// d_ws layout:
//   [0,1024):    int startP[64], cntP[64], startS[64], cntS[64]
//   [1024,4096): float PP[96][8]  (x0,y0,q2,cos | sin,e,b, 0.5*b*ln2)
//   [4096,5632): float SP[96][4]  (x0,y0, -0.5*log2e/sig^2, amp)

__device__ __forceinline__ float fast_atan(float t) {
    float a = __builtin_fabsf(t);
    float r = __builtin_amdgcn_rcpf(a);
    bool big = a > 1.0f;
    float u = big ? r : a;
    float u2 = u * u;
    float p = -0.0117212f;
    p = fmaf(p, u2, 0.05265332f);
    p = fmaf(p, u2, -0.11643287f);
    p = fmaf(p, u2, 0.19354346f);
    p = fmaf(p, u2, -0.33262347f);
    p = fmaf(p, u2, 0.99997726f);
    p = p * u;
    p = big ? (1.57079632679f - p) : p;
    return copysignf(p, t);
}

__global__ void lens_setup(
    const float* __restrict__ pemd_params,    // [NP,6]
    const float* __restrict__ precomp_params, // [NP,4]
    const float* __restrict__ source_params,  // [NS,4]
    const int*   __restrict__ batch_idx,      // [BN]
    const int*   __restrict__ pemd_sys_idx,   // [NP]
    const int*   __restrict__ precomp_map,    // [4]
    const int*   __restrict__ source_sys_idx, // [NS]
    int* __restrict__ ws_i, float* __restrict__ wsP, float* __restrict__ wsS)
{
    __shared__ int sBI[BN];
    __shared__ int nbP[NP], nbS[NS];
    __shared__ int cP[BN], cS[BN], stP[BN], stS[BN];
    const int t = threadIdx.x;  // 128 threads

    if (t < BN) sBI[t] = batch_idx[t];
    __syncthreads();

    if (t < NP) {
        int sys = pemd_sys_idx[t];
        int nb = -1;
        for (int k = 0; k < BN; ++k) if (sBI[k] == sys) { nb = k; break; }
        nbP[t] = nb;
        int sys2 = source_sys_idx[t];
        int nb2 = -1;
        for (int k = 0; k < BN; ++k) if (sBI[k] == sys2) { nb2 = k; break; }
        nbS[t] = nb2;
    }
    __syncthreads();

    if (t < BN) {
        int c = 0, c2 = 0;
        for (int m = 0; m < NP; ++m) { c += (nbP[m] == t); c2 += (nbS[m] == t); }
        cP[t] = c; cS[t] = c2;
    }
    __syncthreads();

    if (t < BN) {
        int s = 0, s2 = 0;
        for (int b = 0; b < t; ++b) { s += cP[b]; s2 += cS[b]; }
        stP[t] = s; stS[t] = s2;
        ws_i[t] = s;        ws_i[64 + t] = cP[t];
        ws_i[128 + t] = s2; ws_i[192 + t] = cS[t];
    }
    __syncthreads();

    if (t < NP) {
        int nb = nbP[t];
        if (nb >= 0) {
            int pos = 0;
            for (int m = 0; m < t; ++m) pos += (nbP[m] == nb);
            const float* p = pemd_params + t * 6;
            float x0 = p[0], y0 = p[1], q = p[2], phi = p[3], thE = p[4];
            float sn, cs;
            __sincosf(phi, &sn, &cs);
            float q2 = q * q;
            float e = sqrtf(fmaxf(1.0f - q2, 1e-8f));
            float scale = precomp_params[t * 4 + precomp_map[0]];
            float bco = thE * scale * q / e;
            int gp = stP[nb] + pos;
            float4* w = (float4*)wsP;
            w[gp * 2]     = make_float4(x0, y0, q2, cs);
            w[gp * 2 + 1] = make_float4(sn, e, bco, bco * 0.34657359f); // 0.5*ln2*b
        }
        int nb2 = nbS[t];
        if (nb2 >= 0) {
            int pos = 0;
            for (int m = 0; m < t; ++m) pos += (nbS[m] == nb2);
            const float* p = source_params + t * 4;
            float sg = p[2];
            // exp(-0.5 r2/sig^2) = exp2(k2p * r2), k2p = -0.5*log2(e)/sig^2
            ((float4*)wsS)[stS[nb2] + pos] =
                make_float4(p[0], p[1], -0.72134752f / (sg * sg), p[3]);
        }
    }
}

__global__ __launch_bounds__(TPB, 8) void lens_main(
    const float* __restrict__ grid,   // [H*W*2] interleaved
    const int*   __restrict__ ws_i,
    const float* __restrict__ wsP,
    const float* __restrict__ wsS,
    float*       __restrict__ out)    // [B,H,W]
{
    const int b = blockIdx.y;
    const int startP = ws_i[b],       nP = ws_i[64 + b];
    const int startS = ws_i[128 + b], nS = ws_i[192 + b];

    const int p = blockIdx.x * TPB + threadIdx.x;      // one pixel per thread
    const float2 g = ((const float2*)grid)[p];
    const float gx = g.x, gy = g.y;

    float dx = 0.f, dy = 0.f;

    const float4* P4 = (const float4*)wsP;
    for (int n = 0; n < nP; ++n) {
        float4 c0 = P4[2 * (startP + n)];
        float4 c1 = P4[2 * (startP + n) + 1];
        float x0 = c0.x, y0 = c0.y, q2 = c0.z, cs = c0.w;
        float sn = c1.x, e = c1.y, bco = c1.z, hb = c1.w;
        float x  = gx - x0;
        float y  = gy - y0;
        float xr = fmaf(cs, x, sn * y);
        float yr = fmaf(cs, y, -(sn * x));
        float h  = fmaf(q2 * xr, xr, yr * yr);
        float rp = __builtin_amdgcn_rsqf(h + 1e-24f);
        float tx = (e * xr) * rp;
        float ty = (e * yr) * rp;
        float ax = bco * fast_atan(tx);
        float tc = fminf(fmaxf(ty, -0.999999f), 0.999999f);
        float L  = __log2f((1.0f + tc) * __builtin_amdgcn_rcpf(1.0f - tc));
        float ay = hb * L;                     // hb = 0.5*ln2*b
        dx = fmaf(cs, ax, dx);
        dx = fmaf(-sn, ay, dx);
        dy = fmaf(sn, ax, dy);
        dy = fmaf(cs, ay, dy);
    }

    const float gxd = gx - dx;
    const float gyd = gy - dy;

    float br = 0.f;
    const float4* S4 = (const float4*)wsS;
    for (int n = 0; n < nS; ++n) {
        float4 sp = S4[startS + n];
        float sx = gxd - sp.x;
        float sy = gyd - sp.y;
        float r2 = fmaf(sx, sx, sy * sy);
        br = fmaf(sp.w, __builtin_amdgcn_exp2f(sp.z * r2), br);
    }

    out[(size_t)b * NPIX + p] = br;
}

extern "C" void kernel_launch(void* const* d_in, const int* in_sizes, int n_in,
                              void* d_out, int out_size, void* d_ws, size_t ws_size,
                              hipStream_t stream) {
    const float* lens_grid      = (const float*)d_in[0];
    const float* pemd_params    = (const float*)d_in[1];
    const float* precomp_params = (const float*)d_in[2];
    const float* source_params  = (const float*)d_in[3];
    const int*   batch_idx      = (const int*)d_in[4];
    const int*   pemd_sys_idx   = (const int*)d_in[5];
    // d_in[6] = precomp_sys_idx (unused by the reference computation)
    const int*   precomp_map    = (const int*)d_in[7];
    const int*   source_sys_idx = (const int*)d_in[8];
    float* out = (float*)d_out;

    int*   ws_i = (int*)d_ws;
    float* wsP  = (float*)((char*)d_ws + 1024);
    float* wsS  = (float*)((char*)d_ws + 4096);

    lens_setup<<<1, 128, 0, stream>>>(pemd_params, precomp_params, source_params,
                                      batch_idx, pemd_sys_idx, precomp_map,
                                      source_sys_idx, ws_i, wsP, wsS);

    dim3 grid(NPIX / TPB, BN, 1);   // 576 x 64 blocks, 1 px/thread
    lens_main<<<grid, TPB, 0, stream>>>(lens_grid, ws_i, wsP, wsS, out);
}

// Round 7
// 40.263 us; speedup vs baseline: 1.2761x; 1.0701x over previous
//
#include <hip/hip_runtime.h>

#define BN 64
#define HH 384
#define WW 384
#define NP 96
#define NS 96
#define NPIX (HH * WW)
#define TPB 256
#define PXT 4                 // x-adjacent pixels per thread (4 | 384 -> same row)
#define PXB (TPB * PXT)       // 1024 px per block
#define NBX (NPIX / PXB)      // 144

// d_ws layout:
//   [0,1024):    int startP[64], cntP[64], startS[64], cntS[64]
//   [1024,4096): float PP[96][8]  (x0,y0,q2,cos | sin,e,b, 0.5*b*ln2)
//   [4096,5632): float SP[96][4]  (x0,y0, -0.5*log2e/sig^2, amp)

__device__ __forceinline__ float fast_atan(float t) {
    float a = __builtin_fabsf(t);
    float r = __builtin_amdgcn_rcpf(a);
    bool big = a > 1.0f;
    float u = big ? r : a;
    float u2 = u * u;
    float p = -0.0117212f;
    p = fmaf(p, u2, 0.05265332f);
    p = fmaf(p, u2, -0.11643287f);
    p = fmaf(p, u2, 0.19354346f);
    p = fmaf(p, u2, -0.33262347f);
    p = fmaf(p, u2, 0.99997726f);
    p = p * u;
    p = big ? (1.57079632679f - p) : p;
    return copysignf(p, t);
}

__global__ void lens_setup(
    const float* __restrict__ pemd_params,    // [NP,6]
    const float* __restrict__ precomp_params, // [NP,4]
    const float* __restrict__ source_params,  // [NS,4]
    const int*   __restrict__ batch_idx,      // [BN]
    const int*   __restrict__ pemd_sys_idx,   // [NP]
    const int*   __restrict__ precomp_map,    // [4]
    const int*   __restrict__ source_sys_idx, // [NS]
    int* __restrict__ ws_i, float* __restrict__ wsP, float* __restrict__ wsS)
{
    __shared__ int sBI[BN];
    __shared__ int nbP[NP], nbS[NS];
    __shared__ int cP[BN], cS[BN], stP[BN], stS[BN];
    const int t = threadIdx.x;  // 128 threads

    if (t < BN) sBI[t] = batch_idx[t];
    __syncthreads();

    if (t < NP) {
        int sys = pemd_sys_idx[t];
        int nb = -1;
        for (int k = 0; k < BN; ++k) if (sBI[k] == sys) { nb = k; break; }
        nbP[t] = nb;
        int sys2 = source_sys_idx[t];
        int nb2 = -1;
        for (int k = 0; k < BN; ++k) if (sBI[k] == sys2) { nb2 = k; break; }
        nbS[t] = nb2;
    }
    __syncthreads();

    if (t < BN) {
        int c = 0, c2 = 0;
        for (int m = 0; m < NP; ++m) { c += (nbP[m] == t); c2 += (nbS[m] == t); }
        cP[t] = c; cS[t] = c2;
    }
    __syncthreads();

    if (t < BN) {
        int s = 0, s2 = 0;
        for (int b = 0; b < t; ++b) { s += cP[b]; s2 += cS[b]; }
        stP[t] = s; stS[t] = s2;
        ws_i[t] = s;        ws_i[64 + t] = cP[t];
        ws_i[128 + t] = s2; ws_i[192 + t] = cS[t];
    }
    __syncthreads();

    if (t < NP) {
        int nb = nbP[t];
        if (nb >= 0) {
            int pos = 0;
            for (int m = 0; m < t; ++m) pos += (nbP[m] == nb);
            const float* p = pemd_params + t * 6;
            float x0 = p[0], y0 = p[1], q = p[2], phi = p[3], thE = p[4];
            float sn, cs;
            __sincosf(phi, &sn, &cs);
            float q2 = q * q;
            float e = sqrtf(fmaxf(1.0f - q2, 1e-8f));
            float scale = precomp_params[t * 4 + precomp_map[0]];
            float bco = thE * scale * q / e;
            int gp = stP[nb] + pos;
            float4* w = (float4*)wsP;
            w[gp * 2]     = make_float4(x0, y0, q2, cs);
            w[gp * 2 + 1] = make_float4(sn, e, bco, bco * 0.34657359f); // 0.5*ln2*b
        }
        int nb2 = nbS[t];
        if (nb2 >= 0) {
            int pos = 0;
            for (int m = 0; m < t; ++m) pos += (nbS[m] == nb2);
            const float* p = source_params + t * 4;
            float sg = p[2];
            // exp(-0.5 r2/sig^2) = exp2(k2p * r2), k2p = -0.5*log2(e)/sig^2
            ((float4*)wsS)[stS[nb2] + pos] =
                make_float4(p[0], p[1], -0.72134752f / (sg * sg), p[3]);
        }
    }
}

__global__ __launch_bounds__(TPB, 4) void lens_main(
    const float* __restrict__ grid,   // [H*W*2] interleaved
    const int*   __restrict__ ws_i,
    const float* __restrict__ wsP,
    const float* __restrict__ wsS,
    float*       __restrict__ out)    // [B,H,W]
{
    const int b = blockIdx.y;
    const int startP = ws_i[b],       nP = ws_i[64 + b];
    const int startS = ws_i[128 + b], nS = ws_i[192 + b];

    // 4 x-adjacent pixels per thread, all in one row -> single gy
    const int po = blockIdx.x * PXB + threadIdx.x * PXT;
    const float4* g4 = (const float4*)(grid + (size_t)po * 2);
    float4 va = g4[0];
    float4 vb = g4[1];
    const float gy = va.y;
    float gx[PXT] = { va.x, va.z, vb.x, vb.z };
    float dx[PXT] = { 0.f, 0.f, 0.f, 0.f };
    float dy[PXT] = { 0.f, 0.f, 0.f, 0.f };

    const float4* P4 = (const float4*)wsP;
    for (int n = 0; n < nP; ++n) {
        float4 c0 = P4[2 * (startP + n)];
        float4 c1 = P4[2 * (startP + n) + 1];
        float x0 = c0.x, y0 = c0.y, q2 = c0.z, cs = c0.w;
        float sn = c1.x, e = c1.y, bco = c1.z, hb = c1.w;
        float A1 = fmaf(sn, gy, -fmaf(sn, y0, cs * x0));   // xr =  cs*gx + A1
        float A2 = fmaf(cs, gy - y0, sn * x0);             // yr = -sn*gx + A2
        #pragma unroll
        for (int u = 0; u < PXT; ++u) {
            float xr = fmaf(cs, gx[u], A1);
            float yr = fmaf(-sn, gx[u], A2);
            float h  = fmaf(q2 * xr, xr, yr * yr);
            float rp = __builtin_amdgcn_rsqf(h + 1e-24f);
            float tx = (e * xr) * rp;
            float ty = (e * yr) * rp;
            float ax = bco * fast_atan(tx);
            float tc = fminf(fmaxf(ty, -0.999999f), 0.999999f);
            float L  = __log2f((1.0f + tc) * __builtin_amdgcn_rcpf(1.0f - tc));
            float ay = hb * L;                 // hb = 0.5*ln2*b
            dx[u] = fmaf(cs, ax, dx[u]);
            dx[u] = fmaf(-sn, ay, dx[u]);
            dy[u] = fmaf(sn, ax, dy[u]);
            dy[u] = fmaf(cs, ay, dy[u]);
        }
    }

    float br[PXT] = { 0.f, 0.f, 0.f, 0.f };
    const float4* S4 = (const float4*)wsS;
    for (int n = 0; n < nS; ++n) {
        float4 sp = S4[startS + n];
        float x0 = sp.x, k2 = sp.z, amp = sp.w;
        float syc = gy - sp.y;
        #pragma unroll
        for (int u = 0; u < PXT; ++u) {
            float sx = (gx[u] - x0) - dx[u];
            float sy = syc - dy[u];
            float r2 = fmaf(sx, sx, sy * sy);
            br[u] = fmaf(amp, __builtin_amdgcn_exp2f(k2 * r2), br[u]);
        }
    }

    *(float4*)(out + (size_t)b * NPIX + po) =
        make_float4(br[0], br[1], br[2], br[3]);
}

extern "C" void kernel_launch(void* const* d_in, const int* in_sizes, int n_in,
                              void* d_out, int out_size, void* d_ws, size_t ws_size,
                              hipStream_t stream) {
    const float* lens_grid      = (const float*)d_in[0];
    const float* pemd_params    = (const float*)d_in[1];
    const float* precomp_params = (const float*)d_in[2];
    const float* source_params  = (const float*)d_in[3];
    const int*   batch_idx      = (const int*)d_in[4];
    const int*   pemd_sys_idx   = (const int*)d_in[5];
    // d_in[6] = precomp_sys_idx (unused by the reference computation)
    const int*   precomp_map    = (const int*)d_in[7];
    const int*   source_sys_idx = (const int*)d_in[8];
    float* out = (float*)d_out;

    int*   ws_i = (int*)d_ws;
    float* wsP  = (float*)((char*)d_ws + 1024);
    float* wsS  = (float*)((char*)d_ws + 4096);

    lens_setup<<<1, 128, 0, stream>>>(pemd_params, precomp_params, source_params,
                                      batch_idx, pemd_sys_idx, precomp_map,
                                      source_sys_idx, ws_i, wsP, wsS);

    dim3 grid(NBX, BN, 1);   // 144 x 64 blocks, 256 thr x 4 px
    lens_main<<<grid, TPB, 0, stream>>>(lens_grid, ws_i, wsP, wsS, out);
}